// Round 1
// 634.917 us; speedup vs baseline: 1.0162x; 1.0162x over previous
//
#include <hip/hip_runtime.h>
#include <hip/hip_bf16.h>
#include <math.h>

#define IN_F    4096
#define OUT_F   4096
#define N_TOK   8192
#define GROUP   128
#define NSTAGE  4
#define NPAIRS  2048   // IN_F/2 pairs per stage
#define QMAXF   15.0

typedef unsigned short u16;
typedef __bf16 bf16x8 __attribute__((ext_vector_type(8)));
typedef float  f32x4  __attribute__((ext_vector_type(4)));

struct alignas(8) U16x4 { u16 x, y, z, w; };

__device__ __forceinline__ u16 f2bf(float f) {
    unsigned u = __float_as_uint(f);
    unsigned r = (u + 0x7fffu + ((u >> 16) & 1u)) >> 16;   // RNE
    return (u16)r;
}

__device__ __forceinline__ void gl_lds16(const void* g, void* l) {
    __builtin_amdgcn_global_load_lds(
        (const __attribute__((address_space(1))) void*)g,
        (__attribute__((address_space(3))) void*)l,
        16, 0, 0);
}

// ---------------------------------------------------------------- tables ----
__global__ void make_tabs(const float* __restrict__ theta,
                          double* __restrict__ ctab, double* __restrict__ stab) {
    int i = blockIdx.x * 256 + threadIdx.x;
    if (i < NSTAGE * NPAIRS) {
        double t = (double)theta[i];
        ctab[i] = cos(t);
        stab[i] = sin(t);
    }
}

// ------------------------------------------------------------- transform ----
// The whole chain (scale -> 4 rot -> qdq -> 4 inv-rot -> unscale) is
// block-diagonal per 128-elem group. One WAVE per (row, group): 1 pair per
// lane per stage, wave-synchronous LDS (no __syncthreads; compiler orders
// may-alias ds ops within the wave). Doubles for fidelity through round().
__global__ __launch_bounds__(256) void build_w(
    const float* __restrict__ weight, const float* __restrict__ cs,
    const float* __restrict__ qs, const float* __restrict__ qzp,
    const int* __restrict__ pairs,
    const double* __restrict__ ctab, const double* __restrict__ stab,
    u16* __restrict__ wb) {
    __shared__ double gbuf[4][GROUP];
    const int wave = threadIdx.x >> 6, l = threadIdx.x & 63;
    const int task = blockIdx.x * 4 + wave;        // 4096*32 tasks
    const int o = task >> 5, g = task & 31;
    double* gb = gbuf[wave];
    const int e0 = g * GROUP;

    float2 wv = *(const float2*)(weight + (size_t)o * IN_F + e0 + 2 * l);
    float2 cv = *(const float2*)(cs + e0 + 2 * l);
    gb[2 * l]     = (double)wv.x * (double)cv.x;
    gb[2 * l + 1] = (double)wv.y * (double)cv.y;
    __builtin_amdgcn_wave_barrier();

    const int2* prs = (const int2*)pairs;          // (i,j) pairs, 8B aligned

    // forward rotation stages
    for (int r = 0; r < NSTAGE; ++r) {
        int2 p = prs[r * (IN_F / 2) + g * 64 + l];
        double c = ctab[r * NPAIRS + g * 64 + l];
        double s = stab[r * NPAIRS + g * 64 + l];
        double xi = gb[p.x], xj = gb[p.y];
        __builtin_amdgcn_wave_barrier();
        gb[p.x] =  xi * c + xj * s;
        gb[p.y] = -xi * s + xj * c;
        __builtin_amdgcn_wave_barrier();
    }

    // group quant-dequant
    {
        double s   = fmin(fmax((double)qs[o * 32 + g], 1e-5), 1e5);
        double rzp = fmin(fmax(-rint((double)qzp[o * 32 + g]), 0.0), QMAXF);
#pragma unroll
        for (int e = 2 * l; e <= 2 * l + 1; ++e) {
            double q = rint(gb[e] / s) + rzp;
            q = fmin(fmax(q, 0.0), QMAXF);
            gb[e] = (q - rzp) * s;
        }
        __builtin_amdgcn_wave_barrier();
    }

    // inverse rotation stages
    for (int r = NSTAGE - 1; r >= 0; --r) {
        int2 p = prs[r * (IN_F / 2) + g * 64 + l];
        double c = ctab[r * NPAIRS + g * 64 + l];
        double s = stab[r * NPAIRS + g * 64 + l];
        double xi = gb[p.x], xj = gb[p.y];
        __builtin_amdgcn_wave_barrier();
        gb[p.x] = xi * c - xj * s;
        gb[p.y] = xi * s + xj * c;
        __builtin_amdgcn_wave_barrier();
    }

    unsigned lo = f2bf((float)(gb[2 * l]     / (double)cv.x));
    unsigned hi = f2bf((float)(gb[2 * l + 1] / (double)cv.y));
    *(unsigned*)(wb + (size_t)o * IN_F + e0 + 2 * l) = lo | (hi << 16);
}

// ----------------------------------------------------------------- cast x ---
__global__ void cast_x(const float* __restrict__ x, u16* __restrict__ xb) {
    size_t i = ((size_t)blockIdx.x * 256 + threadIdx.x) * 4;
    float4 v = *(const float4*)(x + i);
    U16x4 o;
    o.x = f2bf(v.x); o.y = f2bf(v.y); o.z = f2bf(v.z); o.w = f2bf(v.w);
    *(U16x4*)(xb + i) = o;
}

// ------------------------------------------------------------------ GEMM ----
// C[m,n] = sum_k A[m,k] * B[n,k] + bias[n]   (A: M x K, B: N x K, both bf16)
//
// 256x256 tile, 512 thr / 8 waves (2M x 4N, each 128x64), BK=32 sub-tiles in
// a 4-deep LDS ring (128 KiB). Counted-vmcnt pipeline (T3/T4): the main loop
// NEVER drains vmcnt to 0 -- each iteration waits vmcnt(8), which only forces
// retirement of loads issued 3 sub-tiles (~3000 cyc) earlier, then issues the
// next slot's 4 global_load_lds after the barrier. Raw s_barrier (not
// __syncthreads) avoids the compiler's vmcnt(0) drain -- the m97 ceiling.
// LDS chunk-XOR swizzle (2-way max = free; measured 0 conflicts) applied via
// pre-swizzled GLOBAL source (gl_lds writes linearly) + swizzled ds_read.
__global__ __launch_bounds__(512, 2) void gemm_bt(
    const u16* __restrict__ A, const u16* __restrict__ B,
    const float* __restrict__ bias, float* __restrict__ C) {
    constexpr int K = IN_F;
    constexpr int N = OUT_F;
    constexpr int NS = K / 32;                       // 128 sub-tiles
    __shared__ __align__(16) u16 As[4][256 * 32];    // 64 KB
    __shared__ __align__(16) u16 Bs[4][256 * 32];    // 64 KB

    const int tid  = threadIdx.x;
    const int wave = tid >> 6, lane = tid & 63;
    const int lrow = lane & 15, lq = lane >> 4;
    const int wm = wave >> 2, wn = wave & 3;         // 2x4 wave grid

    // XCD-bijective swizzle: 512 wgs, 8 XCDs. Each XCD gets one nt-pair
    // (4 MB of B panels -> L2-resident) across all 32 mt.
    const int wg = (blockIdx.x & 7) * 64 + (blockIdx.x >> 3);
    const int mt = wg & 31, nt = wg >> 5;
    const int m0 = mt * 256, n0 = nt * 256;

    // staging: 512 thr x 16B = 8 KB/round = 128 rows; 2 rounds per operand.
    // LDS dest is linear (gl_lds: wave base + lane*16); global src carries
    // the chunk swizzle: LDS chunk lc of row r holds global chunk lc^((r>>1)&3).
    const int srow = tid >> 2;                              // 0..127
    const int gch  = (tid & 3) ^ ((tid >> 3) & 3);          // swizzled source chunk
    const u16* pA0 = A + (size_t)(m0 + srow) * K + gch * 8;
    const u16* pA1 = pA0 + (size_t)128 * K;
    const u16* pB0 = B + (size_t)(n0 + srow) * K + gch * 8;
    const u16* pB1 = pB0 + (size_t)128 * K;

#define STAGE(slot, s) do {                                         \
        const int ko_ = (s) * 32;                                   \
        gl_lds16(pA0 + ko_, &As[slot][wave * 512]);                 \
        gl_lds16(pA1 + ko_, &As[slot][4096 + wave * 512]);          \
        gl_lds16(pB0 + ko_, &Bs[slot][wave * 512]);                 \
        gl_lds16(pB1 + ko_, &Bs[slot][4096 + wave * 512]);          \
    } while (0)

    f32x4 acc[8][4];
#pragma unroll
    for (int i = 0; i < 8; ++i)
#pragma unroll
        for (int j = 0; j < 4; ++j) acc[i][j] = (f32x4){0.f, 0.f, 0.f, 0.f};

    // prologue: fill 3 ring slots (12 loads in flight)
    STAGE(0, 0); STAGE(1, 1); STAGE(2, 2);

    // Per iteration: wait only for sub-tile s (issued 3 iters ago), barrier,
    // read frags, issue sub-tile s+3 into the slot everyone finished reading
    // last iteration (barrier guarantees), MFMA under setprio(1).
#define BODY(s, VMSTR, DO_STAGE) do {                                          \
        asm volatile("s_waitcnt " VMSTR);                                      \
        __builtin_amdgcn_s_barrier();                                          \
        asm volatile("" ::: "memory");                                         \
        const u16* as_ = As[(s) & 3];                                          \
        const u16* bs_ = Bs[(s) & 3];                                          \
        bf16x8 af[8], bf[4];                                                   \
        _Pragma("unroll")                                                      \
        for (int mi = 0; mi < 8; ++mi) {                                       \
            int ar = wm * 128 + mi * 16 + lrow;                                \
            af[mi] = *(const bf16x8*)&as_[ar * 32 +                            \
                                          (((lq ^ (ar >> 1)) & 3) << 3)];      \
        }                                                                      \
        _Pragma("unroll")                                                      \
        for (int nj = 0; nj < 4; ++nj) {                                       \
            int br = wn * 64 + nj * 16 + lrow;                                 \
            bf[nj] = *(const bf16x8*)&bs_[br * 32 +                            \
                                          (((lq ^ (br >> 1)) & 3) << 3)];      \
        }                                                                      \
        if (DO_STAGE) STAGE(((s) + 3) & 3, (s) + 3);                           \
        __builtin_amdgcn_s_setprio(1);                                         \
        _Pragma("unroll")                                                      \
        for (int mi = 0; mi < 8; ++mi)                                         \
            _Pragma("unroll")                                                  \
            for (int nj = 0; nj < 4; ++nj)                                     \
                acc[mi][nj] = __builtin_amdgcn_mfma_f32_16x16x32_bf16(         \
                    af[mi], bf[nj], acc[mi][nj], 0, 0, 0);                     \
        __builtin_amdgcn_s_setprio(0);                                         \
        asm volatile("" ::: "memory");                                         \
    } while (0)

    for (int s = 0; s < NS - 3; ++s)
        BODY(s, "vmcnt(8)", 1);
    // tail: drain 8 -> 4 -> 0
    BODY(NS - 3, "vmcnt(8)", 0);
    BODY(NS - 2, "vmcnt(4)", 0);
    BODY(NS - 1, "vmcnt(0)", 0);

#undef BODY
#undef STAGE

    // epilogue: C/D layout col = lane&15, row = (lane>>4)*4 + reg
#pragma unroll
    for (int mi = 0; mi < 8; ++mi) {
        int rb = m0 + wm * 128 + mi * 16 + lq * 4;
#pragma unroll
        for (int nj = 0; nj < 4; ++nj) {
            int col = n0 + wn * 64 + nj * 16 + lrow;
            float bv = bias[col];
#pragma unroll
            for (int r = 0; r < 4; ++r)
                C[(size_t)(rb + r) * N + col] = acc[mi][nj][r] + bv;
        }
    }
}

// ---------------------------------------------------------------- launch ----
extern "C" void kernel_launch(void* const* d_in, const int* in_sizes, int n_in,
                              void* d_out, int out_size, void* d_ws, size_t ws_size,
                              hipStream_t stream) {
    const float* x    = (const float*)d_in[0];
    const float* w    = (const float*)d_in[1];
    const float* bias = (const float*)d_in[2];
    const float* cs   = (const float*)d_in[3];
    const float* th   = (const float*)d_in[4];
    const float* qs   = (const float*)d_in[5];
    const float* qzp  = (const float*)d_in[6];
    const int*   pr   = (const int*)d_in[7];
    float* out = (float*)d_out;

    char* ws = (char*)d_ws;
    double* ctab = (double*)ws;                                  // 64 KB
    double* stab = (double*)(ws + 65536);                        // 64 KB
    u16*    xb   = (u16*)(ws + 131072);                          // 64 MB
    u16*    wb   = (u16*)(ws + 131072 + (size_t)N_TOK * IN_F * 2);  // 32 MB

    hipLaunchKernelGGL(make_tabs, dim3((NSTAGE * NPAIRS + 255) / 256), dim3(256),
                       0, stream, th, ctab, stab);
    hipLaunchKernelGGL(build_w, dim3(OUT_F * 32 / 4), dim3(256), 0, stream,
                       w, cs, qs, qzp, pr, ctab, stab, wb);
    hipLaunchKernelGGL(cast_x, dim3(N_TOK * IN_F / 4 / 256), dim3(256), 0, stream,
                       x, xb);
    hipLaunchKernelGGL(gemm_bt, dim3((N_TOK / 256) * (OUT_F / 256)), dim3(512),
                       0, stream, xb, wb, bias, out);
}